// Round 2
// baseline (255.024 us; speedup 1.0000x reference)
//
#include <hip/hip_runtime.h>
#include <math.h>

#define OUTSZ 7
#define SRATE 2
#define B_ 2
#define C_ 256
#define R_ 256
#define N_ (B_ * R_)

// Max patch floats per channel: (roi_w+3)*(roi_h+3) with roi_w*roi_h < 784,
// roi_w <= 128 (level0, 512px box * 0.25)  =>  <= 1195. Pad to 1232.
#define SPAD 1232

struct RoiInfo {
    int lvl, HW, planeBase0, x0, y0, Wp, Hp, S;
    float wy0[14], wy1[14], wx0[14], wx1[14]; // valid mask folded into weights
    short ylr[14], yhr[14], xlr[14], xhr[14]; // bilinear indices relative to patch origin
};

__global__ __launch_bounds__(256) void roi_prep(const float* __restrict__ boxes,
                                                RoiInfo* __restrict__ info)
{
    int n = blockIdx.x * 256 + threadIdx.x;
    if (n >= N_) return;

    const float* bx = boxes + (size_t)n * 4;
    float x1 = bx[0], y1 = bx[1], x2 = bx[2], y2 = bx[3];
    float area = (x2 - x1) * (y2 - y1);
    float lf = floorf(4.0f + log2f(sqrtf(area) / 224.0f + 1e-8f));
    lf = fminf(fmaxf(lf, 2.0f), 5.0f);
    int lvl = (int)lf - 2;

    const float scales[4] = {0.25f, 0.125f, 0.0625f, 0.03125f};
    const int   sizes[4]  = {200, 100, 50, 25};
    float scale = scales[lvl];
    int   HW    = sizes[lvl];

    float fx1 = x1 * scale, fy1 = y1 * scale;
    float roi_w = fmaxf(x2 * scale - fx1, 1.0f);
    float roi_h = fmaxf(y2 * scale - fy1, 1.0f);
    float bw = roi_w / (float)OUTSZ;
    float bh = roi_h / (float)OUTSZ;

    int x0 = max(0, (int)floorf(fx1));
    int y0 = max(0, (int)floorf(fy1));
    int x1p = min(HW - 1, (int)floorf(fx1 + roi_w) + 1);
    int y1p = min(HW - 1, (int)floorf(fy1 + roi_h) + 1);

    RoiInfo ri;
    ri.lvl = lvl;
    ri.HW = HW;
    ri.planeBase0 = (n >> 8) * C_ * HW * HW;   // b * C * H * W
    ri.x0 = x0; ri.y0 = y0;
    ri.Wp = x1p - x0 + 1;
    ri.Hp = y1p - y0 + 1;
    ri.S = ri.Wp * ri.Hp;

    float lim = (float)HW, cap = lim - 1.0f;
    #pragma unroll
    for (int i = 0; i < 14; ++i) {
        float g = (float)(i >> 1) + ((float)(i & 1) + 0.5f) * 0.5f;
        {   // y dimension (torchvision aligned=False _prep)
            float c = fy1 + bh * g;
            bool  v = (c > -1.0f) && (c < lim);
            float cc = fmaxf(c, 0.0f);
            float low = floorf(cc);
            bool  edge = low >= cap;
            low = fminf(low, cap);
            float high = fminf(low + 1.0f, cap);
            float fr = edge ? 0.0f : (cc - low);
            ri.ylr[i] = (short)((int)low - y0);
            ri.yhr[i] = (short)((int)high - y0);
            ri.wy0[i] = v ? (1.0f - fr) : 0.0f;
            ri.wy1[i] = v ? fr : 0.0f;
        }
        {   // x dimension
            float c = fx1 + bw * g;
            bool  v = (c > -1.0f) && (c < lim);
            float cc = fmaxf(c, 0.0f);
            float low = floorf(cc);
            bool  edge = low >= cap;
            low = fminf(low, cap);
            float high = fminf(low + 1.0f, cap);
            float fr = edge ? 0.0f : (cc - low);
            ri.xlr[i] = (short)((int)low - x0);
            ri.xhr[i] = (short)((int)high - x0);
            ri.wx0[i] = v ? (1.0f - fr) : 0.0f;
            ri.wx1[i] = v ? fr : 0.0f;
        }
    }
    info[n] = ri;
}

__global__ __launch_bounds__(256) void roi_main(
    const float* __restrict__ f0, const float* __restrict__ f1,
    const float* __restrict__ f2, const float* __restrict__ f3,
    const RoiInfo* __restrict__ info, float* __restrict__ out)
{
    const int n = blockIdx.y;
    const int cbase = blockIdx.x * 4;
    const int tid = threadIdx.x;

    const RoiInfo& ri = info[n];
    const int HW = ri.HW, Wp = ri.Wp, Hp = ri.Hp, x0 = ri.x0, y0 = ri.y0, S = ri.S;
    const float* fl;
    switch (ri.lvl) {
        case 0:  fl = f0; break;
        case 1:  fl = f1; break;
        case 2:  fl = f2; break;
        default: fl = f3; break;
    }
    const float* base = fl + (size_t)ri.planeBase0;
    const int planeSz = HW * HW;

    __shared__ float patch[4][SPAD];
    const bool staged = (S <= SPAD);   // always true by construction; safety fallback

    if (staged) {
        // Wp in [2,131]; coalesced row-major staging, full line utilization.
        int lw = 32 - __clz(Wp - 1);       // ceil(log2(Wp))
        int xr = tid & ((1 << lw) - 1);
        int yr0 = tid >> lw;
        int rpp = 256 >> lw;               // rows per pass (>=1)
        #pragma unroll
        for (int ch = 0; ch < 4; ++ch) {
            const float* plane = base + (size_t)(cbase + ch) * planeSz;
            if (xr < Wp) {
                for (int y = yr0; y < Hp; y += rpp)
                    patch[ch][y * Wp + xr] = plane[(y0 + y) * HW + x0 + xr];
            }
        }
    }
    __syncthreads();

    if (tid < 196) {
        int ch = tid / 49;
        int cell = tid - ch * 49;
        int oy = cell / 7, ox = cell - oy * 7;
        const float* plane = base + (size_t)(cbase + ch) * planeSz;

        float acc = 0.0f;
        #pragma unroll
        for (int sy = 0; sy < SRATE; ++sy) {
            int ei = oy * 2 + sy;
            float wy0 = ri.wy0[ei], wy1 = ri.wy1[ei];
            int yl = ri.ylr[ei], yh = ri.yhr[ei];
            #pragma unroll
            for (int sx = 0; sx < SRATE; ++sx) {
                int ej = ox * 2 + sx;
                float wx0 = ri.wx0[ej], wx1 = ri.wx1[ej];
                int xl = ri.xlr[ej], xh = ri.xhr[ej];
                float v00, v01, v10, v11;
                if (staged) {
                    v00 = patch[ch][yl * Wp + xl];
                    v01 = patch[ch][yl * Wp + xh];
                    v10 = patch[ch][yh * Wp + xl];
                    v11 = patch[ch][yh * Wp + xh];
                } else {
                    v00 = plane[(y0 + yl) * HW + x0 + xl];
                    v01 = plane[(y0 + yl) * HW + x0 + xh];
                    v10 = plane[(y0 + yh) * HW + x0 + xl];
                    v11 = plane[(y0 + yh) * HW + x0 + xh];
                }
                acc += wy0 * (wx0 * v00 + wx1 * v01) + wy1 * (wx0 * v10 + wx1 * v11);
            }
        }
        out[((size_t)(n * C_ + cbase + ch)) * 49 + cell] = acc * 0.25f;
    }
}

extern "C" void kernel_launch(void* const* d_in, const int* in_sizes, int n_in,
                              void* d_out, int out_size, void* d_ws, size_t ws_size,
                              hipStream_t stream) {
    const float* f0    = (const float*)d_in[0];
    const float* f1    = (const float*)d_in[1];
    const float* f2    = (const float*)d_in[2];
    const float* f3    = (const float*)d_in[3];
    const float* boxes = (const float*)d_in[4];
    float* out = (float*)d_out;
    RoiInfo* info = (RoiInfo*)d_ws;   // 512 * 368B ~= 188 KB

    roi_prep<<<dim3((N_ + 255) / 256), 256, 0, stream>>>(boxes, info);
    roi_main<<<dim3(C_ / 4, N_), 256, 0, stream>>>(f0, f1, f2, f3, info, out);
}

// Round 3
// 243.051 us; speedup vs baseline: 1.0493x; 1.0493x over previous
//
#include <hip/hip_runtime.h>
#include <math.h>

typedef unsigned short u16;
typedef unsigned int   u32;

#define OUTSZ 7
#define B_ 2
#define C_ 256
#define R_ 256
#define N_ (B_ * R_)

// NHWC bf16 scratch layout (pixel index -> 256 bf16 channels)
// level pixel bases (b-major within level): L0:0  L1:80000  L2:100000  L3:105000, total 106250 px
#define PX_TOTAL 106250
#define WS_INFO_OFF 0
#define WS_NHWC_OFF (512 * 1024)            // info uses < 180 KB
#define WS_NEEDED (WS_NHWC_OFF + (size_t)PX_TOTAL * 256 * 2)

struct RoiInfo2 {
    int pxBase, W;
    float wy0[14], wy1[14], wx0[14], wx1[14];  // valid mask folded in
    short yl[14], yh[14], xl[14], xh[14];      // absolute feature coords
};

// ---------------- prep: per-ROI bilinear tables ----------------
__global__ __launch_bounds__(256) void roi_prep(const float* __restrict__ boxes,
                                                RoiInfo2* __restrict__ info)
{
    int n = blockIdx.x * 256 + threadIdx.x;
    if (n >= N_) return;

    const float* bx = boxes + (size_t)n * 4;
    float x1 = bx[0], y1 = bx[1], x2 = bx[2], y2 = bx[3];
    float area = (x2 - x1) * (y2 - y1);
    float lf = floorf(4.0f + log2f(sqrtf(area) / 224.0f + 1e-8f));
    lf = fminf(fmaxf(lf, 2.0f), 5.0f);
    int lvl = (int)lf - 2;

    const float scales[4] = {0.25f, 0.125f, 0.0625f, 0.03125f};
    const int   sizes[4]  = {200, 100, 50, 25};
    const int   bases[4]  = {0, 80000, 100000, 105000};
    float scale = scales[lvl];
    int   HW    = sizes[lvl];
    int   b     = n >> 8;

    float fx1 = x1 * scale, fy1 = y1 * scale;
    float roi_w = fmaxf(x2 * scale - fx1, 1.0f);
    float roi_h = fmaxf(y2 * scale - fy1, 1.0f);
    float bw = roi_w / (float)OUTSZ;
    float bh = roi_h / (float)OUTSZ;

    RoiInfo2 ri;
    ri.W = HW;
    ri.pxBase = bases[lvl] + b * HW * HW;

    float lim = (float)HW, cap = lim - 1.0f;
    #pragma unroll
    for (int i = 0; i < 14; ++i) {
        float g = (float)(i >> 1) + ((float)(i & 1) + 0.5f) * 0.5f;
        {   // y (torchvision aligned=False _prep)
            float c = fy1 + bh * g;
            bool  v = (c > -1.0f) && (c < lim);
            float cc = fmaxf(c, 0.0f);
            float low = floorf(cc);
            bool  edge = low >= cap;
            low = fminf(low, cap);
            float high = fminf(low + 1.0f, cap);
            float fr = edge ? 0.0f : (cc - low);
            ri.yl[i] = (short)(int)low;
            ri.yh[i] = (short)(int)high;
            ri.wy0[i] = v ? (1.0f - fr) : 0.0f;
            ri.wy1[i] = v ? fr : 0.0f;
        }
        {   // x
            float c = fx1 + bw * g;
            bool  v = (c > -1.0f) && (c < lim);
            float cc = fmaxf(c, 0.0f);
            float low = floorf(cc);
            bool  edge = low >= cap;
            low = fminf(low, cap);
            float high = fminf(low + 1.0f, cap);
            float fr = edge ? 0.0f : (cc - low);
            ri.xl[i] = (short)(int)low;
            ri.xh[i] = (short)(int)high;
            ri.wx0[i] = v ? (1.0f - fr) : 0.0f;
            ri.wx1[i] = v ? fr : 0.0f;
        }
    }
    info[n] = ri;
}

// ---------------- NCHW fp32 -> NHWC bf16 transpose/cast ----------------
// grid: (832 flat-pixel tiles across levels, 4 channel tiles, 2 batches), block 256
__global__ __launch_bounds__(256) void nhwc_cast(
    const float* __restrict__ f0, const float* __restrict__ f1,
    const float* __restrict__ f2, const float* __restrict__ f3,
    u16* __restrict__ dst)
{
    int t = blockIdx.x;
    const float* src; int HWsz, dstBase, ft;
    if      (t < 625) { src = f0; HWsz = 40000; dstBase = 0;      ft = t;       }
    else if (t < 782) { src = f1; HWsz = 10000; dstBase = 80000;  ft = t - 625; }
    else if (t < 822) { src = f2; HWsz = 2500;  dstBase = 100000; ft = t - 782; }
    else              { src = f3; HWsz = 625;   dstBase = 105000; ft = t - 822; }

    const int c0 = blockIdx.y * 64;
    const int b  = blockIdx.z;
    const int fbase = ft * 64;

    __shared__ u16 lds[64 * 66];
    const int fx  = threadIdx.x & 63;
    const int sub = threadIdx.x >> 6;

    const float* sp = src + ((size_t)(b * C_ + c0)) * HWsz;
    #pragma unroll
    for (int cL = sub; cL < 64; cL += 4) {
        int f = fbase + fx;
        float v = (f < HWsz) ? sp[(size_t)cL * HWsz + f] : 0.0f;
        u32 u = __float_as_uint(v);
        u += 0x7fffu + ((u >> 16) & 1u);        // RNE to bf16
        lds[fx * 66 + cL] = (u16)(u >> 16);
    }
    __syncthreads();
    const int cc = fx;
    #pragma unroll
    for (int px = sub; px < 64; px += 4) {
        int f = fbase + px;
        if (f < HWsz)
            dst[((size_t)(dstBase + b * HWsz + f)) * 256 + c0 + cc] = lds[px * 66 + cc];
    }
}

// ---------------- main gather: fully coalesced NHWC reads ----------------
// grid (49 cells, 512 rois), block 128 (each thread: 2 packed bf16 channels)
__global__ __launch_bounds__(128) void roi_gather(
    const u16* __restrict__ ws16, const RoiInfo2* __restrict__ info,
    float* __restrict__ out)
{
    const int cell = blockIdx.x;
    const int n    = blockIdx.y;
    const int oy = cell / 7, ox = cell - oy * 7;
    const RoiInfo2& ri = info[n];
    const int W = ri.W, base = ri.pxBase;
    const int c2 = threadIdx.x;

    float acc0 = 0.0f, acc1 = 0.0f;
    #pragma unroll
    for (int sy = 0; sy < 2; ++sy) {
        const int ei = oy * 2 + sy;
        const float wy0 = ri.wy0[ei], wy1 = ri.wy1[ei];
        const int rl = base + ri.yl[ei] * W;
        const int rh = base + ri.yh[ei] * W;
        #pragma unroll
        for (int sx = 0; sx < 2; ++sx) {
            const int ej = ox * 2 + sx;
            const float w00 = wy0 * ri.wx0[ej], w01 = wy0 * ri.wx1[ej];
            const float w10 = wy1 * ri.wx0[ej], w11 = wy1 * ri.wx1[ej];
            const int xl = ri.xl[ej], xh = ri.xh[ej];
            u32 u00 = ((const u32*)(ws16 + (size_t)(rl + xl) * 256))[c2];
            u32 u01 = ((const u32*)(ws16 + (size_t)(rl + xh) * 256))[c2];
            u32 u10 = ((const u32*)(ws16 + (size_t)(rh + xl) * 256))[c2];
            u32 u11 = ((const u32*)(ws16 + (size_t)(rh + xh) * 256))[c2];
            acc0 += w00 * __uint_as_float(u00 << 16) + w01 * __uint_as_float(u01 << 16)
                  + w10 * __uint_as_float(u10 << 16) + w11 * __uint_as_float(u11 << 16);
            acc1 += w00 * __uint_as_float(u00 & 0xffff0000u) + w01 * __uint_as_float(u01 & 0xffff0000u)
                  + w10 * __uint_as_float(u10 & 0xffff0000u) + w11 * __uint_as_float(u11 & 0xffff0000u);
        }
    }
    out[((size_t)(n * C_ + 2 * c2)) * 49 + cell]     = acc0 * 0.25f;
    out[((size_t)(n * C_ + 2 * c2 + 1)) * 49 + cell] = acc1 * 0.25f;
}

// ---------------- fallback: R1 direct-gather (if ws too small) ----------------
__global__ __launch_bounds__(256) void roi_direct(
    const float* __restrict__ f0, const float* __restrict__ f1,
    const float* __restrict__ f2, const float* __restrict__ f3,
    const float* __restrict__ boxes, float* __restrict__ out)
{
    const int total = B_ * R_ * C_ * OUTSZ * OUTSZ;
    int idx = blockIdx.x * blockDim.x + threadIdx.x;
    if (idx >= total) return;
    int ox = idx % 7, oy = (idx / 7) % 7, c = (idx / 49) % C_, n = idx / (49 * C_), b = n >> 8;
    const float* bx = boxes + (size_t)n * 4;
    float x1 = bx[0], y1 = bx[1], x2 = bx[2], y2 = bx[3];
    float lf = floorf(4.0f + log2f(sqrtf((x2 - x1) * (y2 - y1)) / 224.0f + 1e-8f));
    int lvl = (int)fminf(fmaxf(lf, 2.0f), 5.0f) - 2;
    const float scales[4] = {0.25f, 0.125f, 0.0625f, 0.03125f};
    const int sizes[4] = {200, 100, 50, 25};
    float scale = scales[lvl]; int HW = sizes[lvl];
    const float* fl = lvl == 0 ? f0 : lvl == 1 ? f1 : lvl == 2 ? f2 : f3;
    float fx1 = x1 * scale, fy1 = y1 * scale;
    float bw = fmaxf(x2 * scale - fx1, 1.0f) / 7.0f, bh = fmaxf(y2 * scale - fy1, 1.0f) / 7.0f;
    const float* plane = fl + ((size_t)(b * C_ + c)) * HW * HW;
    float lim = (float)HW, cap = lim - 1.0f, acc = 0.0f;
    #pragma unroll
    for (int sy = 0; sy < 2; sy++) {
        float yc = fy1 + bh * ((float)oy + ((float)sy + 0.5f) * 0.5f);
        bool vy = (yc > -1.0f) && (yc < lim);
        float ccy = fmaxf(yc, 0.0f), lowy = floorf(ccy);
        bool ey = lowy >= cap; lowy = fminf(lowy, cap);
        float highy = fminf(lowy + 1.0f, cap);
        float wfy = ey ? 0.0f : (ccy - lowy);
        int yl = (int)lowy, yh = (int)highy;
        #pragma unroll
        for (int sx = 0; sx < 2; sx++) {
            float xc = fx1 + bw * ((float)ox + ((float)sx + 0.5f) * 0.5f);
            bool vx = (xc > -1.0f) && (xc < lim);
            float ccx = fmaxf(xc, 0.0f), lowx = floorf(ccx);
            bool ex = lowx >= cap; lowx = fminf(lowx, cap);
            float highx = fminf(lowx + 1.0f, cap);
            float wfx = ex ? 0.0f : (ccx - lowx);
            int xl = (int)lowx, xh = (int)highx;
            if (vy && vx) {
                float v00 = plane[yl * HW + xl], v01 = plane[yl * HW + xh];
                float v10 = plane[yh * HW + xl], v11 = plane[yh * HW + xh];
                acc += (1.0f - wfy) * ((1.0f - wfx) * v00 + wfx * v01)
                     + wfy * ((1.0f - wfx) * v10 + wfx * v11);
            }
        }
    }
    out[idx] = acc * 0.25f;
}

extern "C" void kernel_launch(void* const* d_in, const int* in_sizes, int n_in,
                              void* d_out, int out_size, void* d_ws, size_t ws_size,
                              hipStream_t stream) {
    const float* f0    = (const float*)d_in[0];
    const float* f1    = (const float*)d_in[1];
    const float* f2    = (const float*)d_in[2];
    const float* f3    = (const float*)d_in[3];
    const float* boxes = (const float*)d_in[4];
    float* out = (float*)d_out;

    if (ws_size < WS_NEEDED) {   // safety fallback
        const int total = B_ * R_ * C_ * OUTSZ * OUTSZ;
        roi_direct<<<(total + 255) / 256, 256, 0, stream>>>(f0, f1, f2, f3, boxes, out);
        return;
    }

    RoiInfo2* info = (RoiInfo2*)((char*)d_ws + WS_INFO_OFF);
    u16*      nhwc = (u16*)((char*)d_ws + WS_NHWC_OFF);

    roi_prep<<<dim3(2), 256, 0, stream>>>(boxes, info);
    nhwc_cast<<<dim3(832, 4, 2), 256, 0, stream>>>(f0, f1, f2, f3, nhwc);
    roi_gather<<<dim3(49, N_), 128, 0, stream>>>(nhwc, info, out);
}

// Round 4
// 233.236 us; speedup vs baseline: 1.0934x; 1.0421x over previous
//
#include <hip/hip_runtime.h>
#include <math.h>

typedef unsigned short u16;
typedef unsigned int   u32;

#define OUTSZ 7
#define B_ 2
#define C_ 256
#define R_ 256
#define N_ (B_ * R_)

// NHWC bf16 scratch: pixel index -> 256 bf16 channels.
// per-batch level pixel bases: L0:0 L1:80000(b-major within level) etc. total 106250 px
#define PX_TOTAL 106250
#define WS_INFO_OFF 0
#define WS_NHWC_OFF (512 * 1024)
#define WS_NEEDED (WS_NHWC_OFF + (size_t)PX_TOTAL * 256 * 2)

struct RoiInfo2 {
    int pxBase, W;
    float wy0[14], wy1[14], wx0[14], wx1[14];  // valid mask folded in
    short yl[14], yh[14], xl[14], xh[14];      // absolute feature coords
};

__device__ __forceinline__ u16 f2bf(float v) {
    u32 u = __float_as_uint(v);
    u += 0x7fffu + ((u >> 16) & 1u);           // RNE to bf16
    return (u16)(u >> 16);
}

// ---------------- prep: per-ROI bilinear tables ----------------
__global__ __launch_bounds__(256) void roi_prep(const float* __restrict__ boxes,
                                                RoiInfo2* __restrict__ info)
{
    int n = blockIdx.x * 256 + threadIdx.x;
    if (n >= N_) return;

    const float* bx = boxes + (size_t)n * 4;
    float x1 = bx[0], y1 = bx[1], x2 = bx[2], y2 = bx[3];
    float area = (x2 - x1) * (y2 - y1);
    float lf = floorf(4.0f + log2f(sqrtf(area) / 224.0f + 1e-8f));
    lf = fminf(fmaxf(lf, 2.0f), 5.0f);
    int lvl = (int)lf - 2;

    const float scales[4] = {0.25f, 0.125f, 0.0625f, 0.03125f};
    const int   sizes[4]  = {200, 100, 50, 25};
    const int   bases[4]  = {0, 80000, 100000, 105000};
    float scale = scales[lvl];
    int   HW    = sizes[lvl];
    int   b     = n >> 8;

    float fx1 = x1 * scale, fy1 = y1 * scale;
    float roi_w = fmaxf(x2 * scale - fx1, 1.0f);
    float roi_h = fmaxf(y2 * scale - fy1, 1.0f);
    float bw = roi_w / (float)OUTSZ;
    float bh = roi_h / (float)OUTSZ;

    RoiInfo2 ri;
    ri.W = HW;
    ri.pxBase = bases[lvl] + b * HW * HW;

    float lim = (float)HW, cap = lim - 1.0f;
    #pragma unroll
    for (int i = 0; i < 14; ++i) {
        float g = (float)(i >> 1) + ((float)(i & 1) + 0.5f) * 0.5f;
        {   // y (torchvision aligned=False _prep)
            float c = fy1 + bh * g;
            bool  v = (c > -1.0f) && (c < lim);
            float cc = fmaxf(c, 0.0f);
            float low = floorf(cc);
            bool  edge = low >= cap;
            low = fminf(low, cap);
            float high = fminf(low + 1.0f, cap);
            float fr = edge ? 0.0f : (cc - low);
            ri.yl[i] = (short)(int)low;
            ri.yh[i] = (short)(int)high;
            ri.wy0[i] = v ? (1.0f - fr) : 0.0f;
            ri.wy1[i] = v ? fr : 0.0f;
        }
        {   // x
            float c = fx1 + bw * g;
            bool  v = (c > -1.0f) && (c < lim);
            float cc = fmaxf(c, 0.0f);
            float low = floorf(cc);
            bool  edge = low >= cap;
            low = fminf(low, cap);
            float high = fminf(low + 1.0f, cap);
            float fr = edge ? 0.0f : (cc - low);
            ri.xl[i] = (short)(int)low;
            ri.xh[i] = (short)(int)high;
            ri.wx0[i] = v ? (1.0f - fr) : 0.0f;
            ri.wx1[i] = v ? fr : 0.0f;
        }
    }
    info[n] = ri;
}

// ---------------- NCHW fp32 -> NHWC bf16, wave-synchronous (no block barrier) ----------------
// 6656 wave-tiles (832 px-tiles x 4 ch-groups x 2 batches); each wave owns a
// private 64px x 64ch LDS tile. grid = 1664 blocks x 256.
__global__ __launch_bounds__(256) void nhwc_cast(
    const float* __restrict__ f0, const float* __restrict__ f1,
    const float* __restrict__ f2, const float* __restrict__ f3,
    u16* __restrict__ dst)
{
    __shared__ u16 lds[4][64 * 68];   // pad 68: 136B rows, 8B-aligned for ushort4
    const int lane = threadIdx.x & 63;
    const int wave = threadIdx.x >> 6;
    u16* L = lds[wave];

    const int wt = blockIdx.x * 4 + wave;     // 0..6655
    const int b  = wt & 1;
    const int cg = (wt >> 1) & 3;
    const int pt = wt >> 3;                   // 0..831 per-batch pixel tile
    const float* src; int HWsz, dstBase, ft;
    if      (pt < 625) { src = f0; HWsz = 40000; dstBase = 0;      ft = pt;       }
    else if (pt < 782) { src = f1; HWsz = 10000; dstBase = 80000;  ft = pt - 625; }
    else if (pt < 822) { src = f2; HWsz = 2500;  dstBase = 100000; ft = pt - 782; }
    else               { src = f3; HWsz = 625;   dstBase = 105000; ft = pt - 822; }
    const int c0 = cg * 64;
    const int fbase = ft * 64;
    const float* sp = src + ((size_t)(b * C_ + c0)) * HWsz;

    // load: lane = pixel, loop channels; coalesced 256B reads; transpose into LDS
    const int f = fbase + lane;
    const bool inb = (f < HWsz);
    #pragma unroll 8
    for (int ch = 0; ch < 64; ++ch) {
        float v = inb ? sp[(size_t)ch * HWsz + f] : 0.0f;
        L[lane * 68 + ch] = f2bf(v);
    }
    __builtin_amdgcn_wave_barrier();   // in-wave LDS RAW; ds ops in-order + compiler waitcnt

    // store: lane -> (16 ch-quads x 4 px-subgroups); ushort4 stores, full line ownership
    const int c4 = (lane & 15) * 4;
    const int pq = lane >> 4;
    #pragma unroll 4
    for (int it = 0; it < 16; ++it) {
        int px = pq + 4 * it;
        int fp = fbase + px;
        if (fp < HWsz) {
            ushort4 v = *(const ushort4*)(&L[px * 68 + c4]);
            *(ushort4*)(dst + ((size_t)(dstBase + b * HWsz + fp)) * 256 + c0 + c4) = v;
        }
    }
}

// ---------------- gather: block owns (ROI n, 128 channels); LDS-transposed store ----------------
// grid (2 cgroups, 512 rois), block 256 (4 waves; wave w handles cells w,w+4,...)
__global__ __launch_bounds__(256) void roi_gather(
    const u16* __restrict__ ws16, const RoiInfo2* __restrict__ info,
    float* __restrict__ out)
{
    __shared__ float lds[128 * 49];            // 25088 B
    const int g    = blockIdx.x;
    const int n    = blockIdx.y;
    const int tid  = threadIdx.x;
    const int lane = tid & 63;
    const int wave = tid >> 6;
    const RoiInfo2& ri = info[n];
    const int W = ri.W, base = ri.pxBase;
    const int c0 = g * 128;

    for (int cell = wave; cell < 49; cell += 4) {
        const int cu = __builtin_amdgcn_readfirstlane(cell);
        const int oy = cu / 7, ox = cu - oy * 7;
        float a0 = 0.0f, a1 = 0.0f;
        #pragma unroll
        for (int sy = 0; sy < 2; ++sy) {
            const int ei = oy * 2 + sy;
            const float wy0 = ri.wy0[ei], wy1 = ri.wy1[ei];
            const int rl = base + ri.yl[ei] * W;
            const int rh = base + ri.yh[ei] * W;
            #pragma unroll
            for (int sx = 0; sx < 2; ++sx) {
                const int ej = ox * 2 + sx;
                const float w00 = wy0 * ri.wx0[ej], w01 = wy0 * ri.wx1[ej];
                const float w10 = wy1 * ri.wx0[ej], w11 = wy1 * ri.wx1[ej];
                const int xl = ri.xl[ej], xh = ri.xh[ej];
                u32 u00 = ((const u32*)(ws16 + (size_t)(rl + xl) * 256 + c0))[lane];
                u32 u01 = ((const u32*)(ws16 + (size_t)(rl + xh) * 256 + c0))[lane];
                u32 u10 = ((const u32*)(ws16 + (size_t)(rh + xl) * 256 + c0))[lane];
                u32 u11 = ((const u32*)(ws16 + (size_t)(rh + xh) * 256 + c0))[lane];
                a0 += w00 * __uint_as_float(u00 << 16) + w01 * __uint_as_float(u01 << 16)
                    + w10 * __uint_as_float(u10 << 16) + w11 * __uint_as_float(u11 << 16);
                a1 += w00 * __uint_as_float(u00 & 0xffff0000u) + w01 * __uint_as_float(u01 & 0xffff0000u)
                    + w10 * __uint_as_float(u10 & 0xffff0000u) + w11 * __uint_as_float(u11 & 0xffff0000u);
            }
        }
        lds[(2 * lane) * 49 + cu]     = a0 * 0.25f;   // 2-way bank alias: free
        lds[(2 * lane + 1) * 49 + cu] = a1 * 0.25f;
    }
    __syncthreads();

    // flat coalesced store: 128ch x 49 cells = 6272 floats, 256B-aligned region
    const float4* lv = (const float4*)lds;
    float4* ov = (float4*)(out + ((size_t)(n * C_ + c0)) * 49);
    for (int i = tid; i < 1568; i += 256) ov[i] = lv[i];
}

// ---------------- fallback: direct gather (if ws too small) ----------------
__global__ __launch_bounds__(256) void roi_direct(
    const float* __restrict__ f0, const float* __restrict__ f1,
    const float* __restrict__ f2, const float* __restrict__ f3,
    const float* __restrict__ boxes, float* __restrict__ out)
{
    const int total = B_ * R_ * C_ * OUTSZ * OUTSZ;
    int idx = blockIdx.x * blockDim.x + threadIdx.x;
    if (idx >= total) return;
    int ox = idx % 7, oy = (idx / 7) % 7, c = (idx / 49) % C_, n = idx / (49 * C_), b = n >> 8;
    const float* bx = boxes + (size_t)n * 4;
    float x1 = bx[0], y1 = bx[1], x2 = bx[2], y2 = bx[3];
    float lf = floorf(4.0f + log2f(sqrtf((x2 - x1) * (y2 - y1)) / 224.0f + 1e-8f));
    int lvl = (int)fminf(fmaxf(lf, 2.0f), 5.0f) - 2;
    const float scales[4] = {0.25f, 0.125f, 0.0625f, 0.03125f};
    const int sizes[4] = {200, 100, 50, 25};
    float scale = scales[lvl]; int HW = sizes[lvl];
    const float* fl = lvl == 0 ? f0 : lvl == 1 ? f1 : lvl == 2 ? f2 : f3;
    float fx1 = x1 * scale, fy1 = y1 * scale;
    float bw = fmaxf(x2 * scale - fx1, 1.0f) / 7.0f, bh = fmaxf(y2 * scale - fy1, 1.0f) / 7.0f;
    const float* plane = fl + ((size_t)(b * C_ + c)) * HW * HW;
    float lim = (float)HW, cap = lim - 1.0f, acc = 0.0f;
    #pragma unroll
    for (int sy = 0; sy < 2; sy++) {
        float yc = fy1 + bh * ((float)oy + ((float)sy + 0.5f) * 0.5f);
        bool vy = (yc > -1.0f) && (yc < lim);
        float ccy = fmaxf(yc, 0.0f), lowy = floorf(ccy);
        bool ey = lowy >= cap; lowy = fminf(lowy, cap);
        float highy = fminf(lowy + 1.0f, cap);
        float wfy = ey ? 0.0f : (ccy - lowy);
        int yl = (int)lowy, yh = (int)highy;
        #pragma unroll
        for (int sx = 0; sx < 2; sx++) {
            float xc = fx1 + bw * ((float)ox + ((float)sx + 0.5f) * 0.5f);
            bool vx = (xc > -1.0f) && (xc < lim);
            float ccx = fmaxf(xc, 0.0f), lowx = floorf(ccx);
            bool ex = lowx >= cap; lowx = fminf(lowx, cap);
            float highx = fminf(lowx + 1.0f, cap);
            float wfx = ex ? 0.0f : (ccx - lowx);
            int xl = (int)lowx, xh = (int)highx;
            if (vy && vx) {
                float v00 = plane[yl * HW + xl], v01 = plane[yl * HW + xh];
                float v10 = plane[yh * HW + xl], v11 = plane[yh * HW + xh];
                acc += (1.0f - wfy) * ((1.0f - wfx) * v00 + wfx * v01)
                     + wfy * ((1.0f - wfx) * v10 + wfx * v11);
            }
        }
    }
    out[idx] = acc * 0.25f;
}

extern "C" void kernel_launch(void* const* d_in, const int* in_sizes, int n_in,
                              void* d_out, int out_size, void* d_ws, size_t ws_size,
                              hipStream_t stream) {
    const float* f0    = (const float*)d_in[0];
    const float* f1    = (const float*)d_in[1];
    const float* f2    = (const float*)d_in[2];
    const float* f3    = (const float*)d_in[3];
    const float* boxes = (const float*)d_in[4];
    float* out = (float*)d_out;

    if (ws_size < WS_NEEDED) {
        const int total = B_ * R_ * C_ * OUTSZ * OUTSZ;
        roi_direct<<<(total + 255) / 256, 256, 0, stream>>>(f0, f1, f2, f3, boxes, out);
        return;
    }

    RoiInfo2* info = (RoiInfo2*)((char*)d_ws + WS_INFO_OFF);
    u16*      nhwc = (u16*)((char*)d_ws + WS_NHWC_OFF);

    roi_prep<<<dim3(2), 256, 0, stream>>>(boxes, info);
    nhwc_cast<<<dim3(1664), 256, 0, stream>>>(f0, f1, f2, f3, nhwc);
    roi_gather<<<dim3(2, N_), 256, 0, stream>>>(nhwc, info, out);
}

// Round 5
// 188.165 us; speedup vs baseline: 1.3553x; 1.2395x over previous
//
#include <hip/hip_runtime.h>
#include <math.h>

typedef unsigned short u16;
typedef unsigned int   u32;

#define OUTSZ 7
#define B_ 2
#define C_ 256
#define R_ 256
#define N_ (B_ * R_)

// NHWC bf16 scratch: pixel index -> 256 bf16 channels (512B records).
// per-batch level pixel bases: L0:0 L1:80000 L2:100000 L3:105000 (b-major within level)
#define PX_TOTAL 106250
#define WS_INFO_OFF 0
#define WS_NHWC_OFF (512 * 1024)
#define WS_NEEDED (WS_NHWC_OFF + (size_t)PX_TOTAL * 256 * 2)

struct RoiInfo2 {
    int pxBase, W;
    float wy0[14], wy1[14], wx0[14], wx1[14];  // valid mask folded in
    short yl[14], yh[14], xl[14], xh[14];      // absolute feature coords
};

__device__ __forceinline__ u16 f2bf(float v) {
    u32 u = __float_as_uint(v);
    u += 0x7fffu + ((u >> 16) & 1u);           // RNE to bf16
    return (u16)(u >> 16);
}

// ---------------- prep: per-ROI bilinear tables ----------------
__global__ __launch_bounds__(256) void roi_prep(const float* __restrict__ boxes,
                                                RoiInfo2* __restrict__ info)
{
    int n = blockIdx.x * 256 + threadIdx.x;
    if (n >= N_) return;

    const float* bx = boxes + (size_t)n * 4;
    float x1 = bx[0], y1 = bx[1], x2 = bx[2], y2 = bx[3];
    float area = (x2 - x1) * (y2 - y1);
    float lf = floorf(4.0f + log2f(sqrtf(area) / 224.0f + 1e-8f));
    lf = fminf(fmaxf(lf, 2.0f), 5.0f);
    int lvl = (int)lf - 2;

    const float scales[4] = {0.25f, 0.125f, 0.0625f, 0.03125f};
    const int   sizes[4]  = {200, 100, 50, 25};
    const int   bases[4]  = {0, 80000, 100000, 105000};
    float scale = scales[lvl];
    int   HW    = sizes[lvl];
    int   b     = n >> 8;

    float fx1 = x1 * scale, fy1 = y1 * scale;
    float roi_w = fmaxf(x2 * scale - fx1, 1.0f);
    float roi_h = fmaxf(y2 * scale - fy1, 1.0f);
    float bw = roi_w / (float)OUTSZ;
    float bh = roi_h / (float)OUTSZ;

    RoiInfo2 ri;
    ri.W = HW;
    ri.pxBase = bases[lvl] + b * HW * HW;

    float lim = (float)HW, cap = lim - 1.0f;
    #pragma unroll
    for (int i = 0; i < 14; ++i) {
        float g = (float)(i >> 1) + ((float)(i & 1) + 0.5f) * 0.5f;
        {   // y (torchvision aligned=False _prep)
            float c = fy1 + bh * g;
            bool  v = (c > -1.0f) && (c < lim);
            float cc = fmaxf(c, 0.0f);
            float low = floorf(cc);
            bool  edge = low >= cap;
            low = fminf(low, cap);
            float high = fminf(low + 1.0f, cap);
            float fr = edge ? 0.0f : (cc - low);
            ri.yl[i] = (short)(int)low;
            ri.yh[i] = (short)(int)high;
            ri.wy0[i] = v ? (1.0f - fr) : 0.0f;
            ri.wy1[i] = v ? fr : 0.0f;
        }
        {   // x
            float c = fx1 + bw * g;
            bool  v = (c > -1.0f) && (c < lim);
            float cc = fmaxf(c, 0.0f);
            float low = floorf(cc);
            bool  edge = low >= cap;
            low = fminf(low, cap);
            float high = fminf(low + 1.0f, cap);
            float fr = edge ? 0.0f : (cc - low);
            ri.xl[i] = (short)(int)low;
            ri.xh[i] = (short)(int)high;
            ri.wx0[i] = v ? (1.0f - fr) : 0.0f;
            ri.wx1[i] = v ? fr : 0.0f;
        }
    }
    info[n] = ri;
}

// ---------------- NCHW fp32 -> NHWC bf16: block-cooperative 64ch x 256px tile ----
// Loads: one wave instruction = full channel row (64 lanes x float4 = 1KB contig);
// 16 independent loads/thread for MLP. LDS ch-major, px b64 writes (conflict-free).
// Stores: 8px x 128B full-line segments per instruction (uint4).
// grid = (210 px-tiles, 4 ch-blocks, 2 batches), block 256.
__global__ __launch_bounds__(256) void nhwc_cast(
    const float* __restrict__ f0, const float* __restrict__ f1,
    const float* __restrict__ f2, const float* __restrict__ f3,
    u16* __restrict__ dst)
{
    __shared__ u16 T[64 * 260];   // ch-major, px-stride 260 (520B rows, 8B aligned)
    const int tid  = threadIdx.x;
    const int lane = tid & 63;
    const int wave = tid >> 6;

    const int t  = blockIdx.x;
    const int cb = blockIdx.y;
    const int b  = blockIdx.z;
    const float* src; int HWsz, dstBase, ft;
    if      (t < 157) { src = f0; HWsz = 40000; dstBase = 0;      ft = t;       }
    else if (t < 197) { src = f1; HWsz = 10000; dstBase = 80000;  ft = t - 157; }
    else if (t < 207) { src = f2; HWsz = 2500;  dstBase = 100000; ft = t - 197; }
    else              { src = f3; HWsz = 625;   dstBase = 105000; ft = t - 207; }

    const int fbase = ft * 256;
    const int c0    = cb * 64;
    const int rem   = HWsz - fbase;            // >= 1
    const int p0    = 4 * lane;
    const bool vec  = ((HWsz & 3) == 0) && (p0 + 3 < rem);   // loop-invariant

    #pragma unroll
    for (int i = 0; i < 16; ++i) {
        const int ch = i * 4 + wave;
        const float* row = src + ((size_t)(b * C_ + c0 + ch)) * HWsz + fbase;
        ushort4 v;
        if (vec) {
            float4 f = *(const float4*)(row + p0);
            v.x = f2bf(f.x); v.y = f2bf(f.y); v.z = f2bf(f.z); v.w = f2bf(f.w);
        } else {
            float a0 = (p0 + 0 < rem) ? row[p0 + 0] : 0.0f;
            float a1 = (p0 + 1 < rem) ? row[p0 + 1] : 0.0f;
            float a2 = (p0 + 2 < rem) ? row[p0 + 2] : 0.0f;
            float a3 = (p0 + 3 < rem) ? row[p0 + 3] : 0.0f;
            v.x = f2bf(a0); v.y = f2bf(a1); v.z = f2bf(a2); v.w = f2bf(a3);
        }
        *(ushort4*)(&T[ch * 260 + p0]) = v;    // ds_write_b64, conflict-free
    }
    __syncthreads();

    const int maxpx = rem < 256 ? rem : 256;
    #pragma unroll
    for (int i = 0; i < 8; ++i) {
        const int idx = i * 256 + tid;
        const int px  = idx >> 3;
        const int sub = idx & 7;
        if (px < maxpx) {
            const u16* tp = &T[(sub * 8) * 260 + px];
            uint4 o;
            o.x = (u32)tp[0]    | ((u32)tp[260]  << 16);
            o.y = (u32)tp[520]  | ((u32)tp[780]  << 16);
            o.z = (u32)tp[1040] | ((u32)tp[1300] << 16);
            o.w = (u32)tp[1560] | ((u32)tp[1820] << 16);
            *(uint4*)(dst + ((size_t)(dstBase + b * HWsz + fbase + px)) * 256 + c0 + sub * 8) = o;
        }
    }
}

// ---------------- gather: block owns (ROI n, 128 channels); LDS-transposed store ----
__global__ __launch_bounds__(256) void roi_gather(
    const u16* __restrict__ ws16, const RoiInfo2* __restrict__ info,
    float* __restrict__ out)
{
    __shared__ float lds[128 * 49];            // 25088 B
    const int g    = blockIdx.x;
    const int n    = blockIdx.y;
    const int tid  = threadIdx.x;
    const int lane = tid & 63;
    const int wave = tid >> 6;
    const RoiInfo2& ri = info[n];
    const int W = ri.W, base = ri.pxBase;
    const int c0 = g * 128;

    for (int cell = wave; cell < 49; cell += 4) {
        const int cu = __builtin_amdgcn_readfirstlane(cell);
        const int oy = cu / 7, ox = cu - oy * 7;
        float a0 = 0.0f, a1 = 0.0f;
        #pragma unroll
        for (int sy = 0; sy < 2; ++sy) {
            const int ei = oy * 2 + sy;
            const float wy0 = ri.wy0[ei], wy1 = ri.wy1[ei];
            const int rl = base + ri.yl[ei] * W;
            const int rh = base + ri.yh[ei] * W;
            #pragma unroll
            for (int sx = 0; sx < 2; ++sx) {
                const int ej = ox * 2 + sx;
                const float w00 = wy0 * ri.wx0[ej], w01 = wy0 * ri.wx1[ej];
                const float w10 = wy1 * ri.wx0[ej], w11 = wy1 * ri.wx1[ej];
                const int xl = ri.xl[ej], xh = ri.xh[ej];
                u32 u00 = ((const u32*)(ws16 + (size_t)(rl + xl) * 256 + c0))[lane];
                u32 u01 = ((const u32*)(ws16 + (size_t)(rl + xh) * 256 + c0))[lane];
                u32 u10 = ((const u32*)(ws16 + (size_t)(rh + xl) * 256 + c0))[lane];
                u32 u11 = ((const u32*)(ws16 + (size_t)(rh + xh) * 256 + c0))[lane];
                a0 += w00 * __uint_as_float(u00 << 16) + w01 * __uint_as_float(u01 << 16)
                    + w10 * __uint_as_float(u10 << 16) + w11 * __uint_as_float(u11 << 16);
                a1 += w00 * __uint_as_float(u00 & 0xffff0000u) + w01 * __uint_as_float(u01 & 0xffff0000u)
                    + w10 * __uint_as_float(u10 & 0xffff0000u) + w11 * __uint_as_float(u11 & 0xffff0000u);
            }
        }
        lds[(2 * lane) * 49 + cu]     = a0 * 0.25f;
        lds[(2 * lane + 1) * 49 + cu] = a1 * 0.25f;
    }
    __syncthreads();

    const float4* lv = (const float4*)lds;
    float4* ov = (float4*)(out + ((size_t)(n * C_ + c0)) * 49);
    for (int i = tid; i < 1568; i += 256) ov[i] = lv[i];
}

// ---------------- fallback: direct gather (if ws too small) ----------------
__global__ __launch_bounds__(256) void roi_direct(
    const float* __restrict__ f0, const float* __restrict__ f1,
    const float* __restrict__ f2, const float* __restrict__ f3,
    const float* __restrict__ boxes, float* __restrict__ out)
{
    const int total = B_ * R_ * C_ * OUTSZ * OUTSZ;
    int idx = blockIdx.x * blockDim.x + threadIdx.x;
    if (idx >= total) return;
    int ox = idx % 7, oy = (idx / 7) % 7, c = (idx / 49) % C_, n = idx / (49 * C_), b = n >> 8;
    const float* bx = boxes + (size_t)n * 4;
    float x1 = bx[0], y1 = bx[1], x2 = bx[2], y2 = bx[3];
    float lf = floorf(4.0f + log2f(sqrtf((x2 - x1) * (y2 - y1)) / 224.0f + 1e-8f));
    int lvl = (int)fminf(fmaxf(lf, 2.0f), 5.0f) - 2;
    const float scales[4] = {0.25f, 0.125f, 0.0625f, 0.03125f};
    const int sizes[4] = {200, 100, 50, 25};
    float scale = scales[lvl]; int HW = sizes[lvl];
    const float* fl = lvl == 0 ? f0 : lvl == 1 ? f1 : lvl == 2 ? f2 : f3;
    float fx1 = x1 * scale, fy1 = y1 * scale;
    float bw = fmaxf(x2 * scale - fx1, 1.0f) / 7.0f, bh = fmaxf(y2 * scale - fy1, 1.0f) / 7.0f;
    const float* plane = fl + ((size_t)(b * C_ + c)) * HW * HW;
    float lim = (float)HW, cap = lim - 1.0f, acc = 0.0f;
    #pragma unroll
    for (int sy = 0; sy < 2; sy++) {
        float yc = fy1 + bh * ((float)oy + ((float)sy + 0.5f) * 0.5f);
        bool vy = (yc > -1.0f) && (yc < lim);
        float ccy = fmaxf(yc, 0.0f), lowy = floorf(ccy);
        bool ey = lowy >= cap; lowy = fminf(lowy, cap);
        float highy = fminf(lowy + 1.0f, cap);
        float wfy = ey ? 0.0f : (ccy - lowy);
        int yl = (int)lowy, yh = (int)highy;
        #pragma unroll
        for (int sx = 0; sx < 2; sx++) {
            float xc = fx1 + bw * ((float)ox + ((float)sx + 0.5f) * 0.5f);
            bool vx = (xc > -1.0f) && (xc < lim);
            float ccx = fmaxf(xc, 0.0f), lowx = floorf(ccx);
            bool ex = lowx >= cap; lowx = fminf(lowx, cap);
            float highx = fminf(lowx + 1.0f, cap);
            float wfx = ex ? 0.0f : (ccx - lowx);
            int xl = (int)lowx, xh = (int)highx;
            if (vy && vx) {
                float v00 = plane[yl * HW + xl], v01 = plane[yl * HW + xh];
                float v10 = plane[yh * HW + xl], v11 = plane[yh * HW + xh];
                acc += (1.0f - wfy) * ((1.0f - wfx) * v00 + wfx * v01)
                     + wfy * ((1.0f - wfx) * v10 + wfx * v11);
            }
        }
    }
    out[idx] = acc * 0.25f;
}

extern "C" void kernel_launch(void* const* d_in, const int* in_sizes, int n_in,
                              void* d_out, int out_size, void* d_ws, size_t ws_size,
                              hipStream_t stream) {
    const float* f0    = (const float*)d_in[0];
    const float* f1    = (const float*)d_in[1];
    const float* f2    = (const float*)d_in[2];
    const float* f3    = (const float*)d_in[3];
    const float* boxes = (const float*)d_in[4];
    float* out = (float*)d_out;

    if (ws_size < WS_NEEDED) {
        const int total = B_ * R_ * C_ * OUTSZ * OUTSZ;
        roi_direct<<<(total + 255) / 256, 256, 0, stream>>>(f0, f1, f2, f3, boxes, out);
        return;
    }

    RoiInfo2* info = (RoiInfo2*)((char*)d_ws + WS_INFO_OFF);
    u16*      nhwc = (u16*)((char*)d_ws + WS_NHWC_OFF);

    roi_prep<<<dim3(2), 256, 0, stream>>>(boxes, info);
    nhwc_cast<<<dim3(210, 4, 2), 256, 0, stream>>>(f0, f1, f2, f3, nhwc);
    roi_gather<<<dim3(2, N_), 256, 0, stream>>>(nhwc, info, out);
}